// Round 7
// baseline (231.786 us; speedup 1.0000x reference)
//
#include <hip/hip_runtime.h>
#include <hip/hip_bf16.h>

typedef __attribute__((ext_vector_type(8))) short short8;
typedef __attribute__((ext_vector_type(4))) short short4v;
typedef __attribute__((ext_vector_type(4))) float f32x4;

__device__ __forceinline__ short f2bf(float f) {
    union { float f; unsigned u; } v; v.f = f;
    unsigned r = (v.u + 0x7fffu + ((v.u >> 16) & 1u)) >> 16;
    return (short)r;
}
__device__ __forceinline__ float bf2f(short s) {
    union { unsigned u; float f; } v; v.u = ((unsigned)(unsigned short)s) << 16;
    return v.f;
}
__device__ __forceinline__ f32x4 zero4() { f32x4 z = {0.f, 0.f, 0.f, 0.f}; return z; }

// ---------------------------------------------------------------------------
// convertA v2: fp32 -> bf16 in MFMA-FRAGMENT-MAJOR layout.
// Fragment = 16 rows x 32 k-cols; frag idx f = (row>>4)*48 + (k>>5);
// elem (lane*8+e) <-> (row = l15, k = quad*8+e). One wave <-> one fragment:
// reads 16 rows x 128 B (sector-coalesced), writes 1 KB contiguous.
// z=0: qbF  z=1: kbF  z=2: WqbF (rows 0..511)  z=3: WkbF
// ---------------------------------------------------------------------------
__global__ __launch_bounds__(256) void convertA_kernel(
    const float* __restrict__ q, const float* __restrict__ k,
    const float* __restrict__ Wq, const float* __restrict__ Wk,
    short* __restrict__ qb, short* __restrict__ kb,
    short* __restrict__ Wqb, short* __restrict__ Wkb)
{
    const int tid = threadIdx.x;
    const int w = tid >> 6;
    const int lane = tid & 63;
    const int l15 = lane & 15;
    const int quad = lane >> 4;
    const int f = blockIdx.x * 4 + w;          // fragment index (wave-uniform)
    const float* src; short* dst; int nfrag;
    switch (blockIdx.z) {
    case 0:  nfrag = 12288; src = q;  dst = qb;  break;   // 256 r16 x 48 kt
    case 1:  nfrag = 12288; src = k;  dst = kb;  break;
    case 2:  nfrag = 1536;  src = Wq; dst = Wqb; break;   // 32 r16 x 48 kt
    default: nfrag = 1536;  src = Wk; dst = Wkb; break;
    }
    if (f >= nfrag) return;
    const int r16 = f / 48;
    const int kt  = f - r16 * 48;
    const float* s = src + (size_t)(r16 * 16 + l15) * 1536 + kt * 32 + quad * 8;
    const float4 a = ((const float4*)s)[0];
    const float4 b = ((const float4*)s)[1];
    short8 o;
    o[0]=f2bf(a.x); o[1]=f2bf(a.y); o[2]=f2bf(a.z); o[3]=f2bf(a.w);
    o[4]=f2bf(b.x); o[5]=f2bf(b.y); o[6]=f2bf(b.z); o[7]=f2bf(b.w);
    *(short8*)(dst + (size_t)f * 512 + lane * 8) = o;
}

// ---------------------------------------------------------------------------
// proj z0/z1 v2: NO-LDS direct-fragment GEMM (round-6 flash pattern applied
// to GEMM). A (qbF/kbF) and B (WqbF/WkbF) are fragment-major in global: every
// operand fragment is ONE coalesced global_load_dwordx4, no barriers, no LDS,
// no gl16 serialization. Tile BM=128 x BN=64, waves 2x2 (64x32 each),
// acc[4][2]. Flat-id decode keeps grid (4,64,z): 256 tiles -> 768 blocks
// total = 3/CU, each CU gets one z0 + one z1 + one z2 block (uniform work).
// RoPE epilogue unchanged. MODE 1: row-major qh (ldc=512). MODE 2:
// fragment-major khF (round-6 proven formula).
// ---------------------------------------------------------------------------
template<int MODE>
__device__ __forceinline__ void gemm_frag_direct(
    const short* __restrict__ Af, const short* __restrict__ Bf, short* __restrict__ Cp)
{
    const int flat = blockIdx.x + (blockIdx.y << 2);   // 0..255
    const int bm = (flat >> 3) * 128;
    const int bn = (flat & 7) * 64;
    const int tid = threadIdx.x;
    const int w = tid >> 6;
    const int lane = tid & 63;
    const int l15 = lane & 15;
    const int quad = lane >> 4;
    const int wm = (w >> 1) * 64;
    const int wn = (w & 1) * 32;

    const short* ab = Af + (size_t)((bm + wm) >> 4) * 24576 + lane * 8;
    const short* bb = Bf + (size_t)((bn + wn) >> 4) * 24576 + lane * 8;

    f32x4 acc[4][2];
#pragma unroll
    for (int i = 0; i < 4; i++)
#pragma unroll
        for (int j = 0; j < 2; j++) acc[i][j] = zero4();

#pragma unroll 2
    for (int kt = 0; kt < 48; ++kt) {
        short8 af[4], bf[2];
#pragma unroll
        for (int i = 0; i < 4; i++)
            af[i] = *(const short8*)(ab + i * 24576 + kt * 512);
#pragma unroll
        for (int j = 0; j < 2; j++)
            bf[j] = *(const short8*)(bb + j * 24576 + kt * 512);
#pragma unroll
        for (int i = 0; i < 4; i++)
#pragma unroll
            for (int j = 0; j < 2; j++)
                acc[i][j] = __builtin_amdgcn_mfma_f32_16x16x32_bf16(af[i], bf[j], acc[i][j], 0, 0, 0);
    }

#pragma unroll
    for (int i = 0; i < 4; i++)
#pragma unroll
        for (int j = 0; j < 2; j++) {
            const int col = bn + wn + j * 16 + l15;
            const int row0 = bm + wm + i * 16 + quad * 4;
            const int pairi = (col & 127) >> 1;   // same for both lanes of a pair
            const float freq = exp2f(-(float)(2 * pairi) * (13.287712379549449f / 128.0f));
            const bool even = (l15 & 1) == 0;
#pragma unroll
            for (int r = 0; r < 4; r++) {
                const float own = acc[i][j][r];
                const float other = __shfl_xor(own, 1, 64);
                const float pos = (float)((row0 + r) & 2047);
                const float ang = pos * freq;
                const float n = rintf(ang * 0.15915494309189535f);
                const float rr = (ang - n * 6.28125f) - n * 1.9353071795864769e-3f;
                float s, c;
                __sincosf(rr, &s, &c);
                const float x1 = even ? own : other;
                const float x2 = even ? other : own;
                const float res = even ? (x1 * c - x2 * s) : (x1 * s + x2 * c);
                if constexpr (MODE == 1) {
                    Cp[(size_t)(row0 + r) * 512 + col] = f2bf(res);
                } else {
                    const int seq = row0 + r;
                    const int b_ = seq >> 11;
                    const int s2 = seq & 2047;
                    Cp[(size_t)(b_ * 4 + (col >> 7)) * 262144 + (s2 >> 5) * 4096
                       + ((s2 >> 4) & 1) * 2048 + ((col >> 5) & 3) * 512
                       + ((col >> 3) & 3) * 128 + (s2 & 15) * 8 + (col & 7)] = f2bf(res);
                }
            }
        }
}

// ---------------------------------------------------------------------------
// fp32-input GEMM, BM=64 BN=128 BK=32 (proven core), MFMA-fragment-major V
// store (vF) for coalesced flash V-operand loads. UNCHANGED from round 6.
// ---------------------------------------------------------------------------
__device__ __forceinline__ void gemm_f32T_vF(
    const float* __restrict__ A, const float* __restrict__ Bw, short* __restrict__ Cp,
    int K, int lda, int ldb, short* As, short* Bs)
{
    const int bm = blockIdx.y * 64;
    const int bn = blockIdx.x * 128;
    const int tid = threadIdx.x;
    const int w = tid >> 6;
    const int lane = tid & 63;
    const int l15 = lane & 15;
    const int quad = lane >> 4;
    const int wm = (w >> 1) * 32;
    const int wn = (w & 1) * 64;
    const int srA = tid >> 2;
    const int scA = (tid & 3) * 8;
    const int srB = tid >> 1;
    const int scB = (tid & 1) * 16;

    f32x4 acc[2][4];
#pragma unroll
    for (int i = 0; i < 2; i++)
#pragma unroll
        for (int j = 0; j < 4; j++) acc[i][j] = zero4();

    for (int k0 = 0; k0 < K; k0 += 32) {
        __syncthreads();
        {
            const float* src = A + (size_t)(bm + srA) * lda + k0 + scA;
            short* dst = &As[srA * 40 + scA];
            const float4* s4 = (const float4*)src;
            float4 f0 = s4[0], f1 = s4[1];
            short8 t0;
            t0[0]=f2bf(f0.x); t0[1]=f2bf(f0.y); t0[2]=f2bf(f0.z); t0[3]=f2bf(f0.w);
            t0[4]=f2bf(f1.x); t0[5]=f2bf(f1.y); t0[6]=f2bf(f1.z); t0[7]=f2bf(f1.w);
            *(short8*)dst = t0;
        }
        {
            const float* src = Bw + (size_t)(bn + srB) * ldb + k0 + scB;
            short* dst = &Bs[srB * 40 + scB];
            const float4* s4 = (const float4*)src;
            float4 f0 = s4[0], f1 = s4[1], f2 = s4[2], f3 = s4[3];
            short8 t0, t1;
            t0[0]=f2bf(f0.x); t0[1]=f2bf(f0.y); t0[2]=f2bf(f0.z); t0[3]=f2bf(f0.w);
            t0[4]=f2bf(f1.x); t0[5]=f2bf(f1.y); t0[6]=f2bf(f1.z); t0[7]=f2bf(f1.w);
            t1[0]=f2bf(f2.x); t1[1]=f2bf(f2.y); t1[2]=f2bf(f2.z); t1[3]=f2bf(f2.w);
            t1[4]=f2bf(f3.x); t1[5]=f2bf(f3.y); t1[6]=f2bf(f3.z); t1[7]=f2bf(f3.w);
            *(short8*)dst = t0; *(short8*)(dst + 8) = t1;
        }
        __syncthreads();

        short8 af[2], bfr[4];
#pragma unroll
        for (int i = 0; i < 2; i++)
            af[i] = *(const short8*)&As[(wm + i * 16 + l15) * 40 + quad * 8];
#pragma unroll
        for (int j = 0; j < 4; j++)
            bfr[j] = *(const short8*)&Bs[(wn + j * 16 + l15) * 40 + quad * 8];
#pragma unroll
        for (int i = 0; i < 2; i++)
#pragma unroll
            for (int j = 0; j < 4; j++)
                acc[i][j] = __builtin_amdgcn_mfma_f32_16x16x32_bf16(af[i], bfr[j], acc[i][j], 0, 0, 0);
    }

#pragma unroll
    for (int i = 0; i < 2; i++)
#pragma unroll
        for (int j = 0; j < 4; j++) {
            const int col = bn + wn + j * 16 + l15;     // d feature 0..511
            const int row0 = bm + wm + i * 16 + quad * 4; // kv seq 0..4095
            const int b_ = row0 >> 11;
            const int s2 = row0 & 2047;
            short4v p;
#pragma unroll
            for (int r = 0; r < 4; r++) p[r] = f2bf(acc[i][j][r]);
            const size_t addr = (size_t)(b_ * 4 + (col >> 7)) * 262144 + (s2 >> 5) * 4096
                              + ((col >> 4) & 7) * 512 + ((s2 >> 3) & 3) * 128
                              + (col & 15) * 8 + (s2 & 7);
            *(short4v*)&Cp[addr] = p;
        }
}

// z=0: qh = rope(qbF@WqbF^T) direct-frag; z=1: khF likewise; z=2: vT fp32 core.
// Grid (4, 64, 3) = 768 blocks = 3/CU; every CU runs one z0 + one z1 + one z2.
__global__ __launch_bounds__(256) void proj_kernel(
    const short* __restrict__ qb, const short* __restrict__ kb, const float* __restrict__ v,
    const short* __restrict__ Wqb, const short* __restrict__ Wkb, const float* __restrict__ Wv,
    short* __restrict__ qh, short* __restrict__ khF, short* __restrict__ vF)
{
    __shared__ short smem[12288];   // used by z2 only
    switch (blockIdx.z) {
    case 0:  gemm_frag_direct<1>(qb, Wqb, qh); break;
    case 1:  gemm_frag_direct<2>(kb, Wkb, khF); break;
    default: gemm_f32T_vF(v + 512, Wv, vF, 512, 1536, 512, smem, smem + 2560); break;
    }
}

// out[4096,1536] = attn[4096,512] @ Wo[:, :512]^T — convertB fused (B fp32 staging)
__global__ __launch_bounds__(256) void outproj_kernel(
    const short* __restrict__ attn, const float* __restrict__ Wo, float* __restrict__ out)
{
    __shared__ short smem[2][5120];
    const int bm = blockIdx.y * 128;
    const int bn = blockIdx.x * 128;
    const int tid = threadIdx.x;
    const int w = tid >> 6;
    const int lane = tid & 63;
    const int l15 = lane & 15;
    const int quad = lane >> 4;
    const int wm = (w >> 1) * 64;
    const int wn = (w & 1) * 64;
    const int srow = tid >> 1;
    const int scol = (tid & 1) * 16;
    short* As = smem[0];
    short* Bs = smem[1];
    const int K = 512, lda = 512, ldb = 1536, ldc = 1536;

    f32x4 acc[4][4];
#pragma unroll
    for (int i = 0; i < 4; i++)
#pragma unroll
        for (int j = 0; j < 4; j++) acc[i][j] = zero4();

    for (int k0 = 0; k0 < K; k0 += 32) {
        __syncthreads();
        {
            const short* src = attn + (size_t)(bm + srow) * lda + k0 + scol;
            short* dst = &As[srow * 40 + scol];
            const uint4* s4 = (const uint4*)src;
            uint4 a = s4[0], b = s4[1];
            *(uint4*)dst = a; *(uint4*)(dst + 8) = b;
        }
        {
            const float* src = Wo + (size_t)(bn + srow) * ldb + k0 + scol;
            short* dst = &Bs[srow * 40 + scol];
            const float4* s4 = (const float4*)src;
            float4 f0 = s4[0], f1 = s4[1], f2 = s4[2], f3 = s4[3];
            short8 t0, t1;
            t0[0]=f2bf(f0.x); t0[1]=f2bf(f0.y); t0[2]=f2bf(f0.z); t0[3]=f2bf(f0.w);
            t0[4]=f2bf(f1.x); t0[5]=f2bf(f1.y); t0[6]=f2bf(f1.z); t0[7]=f2bf(f1.w);
            t1[0]=f2bf(f2.x); t1[1]=f2bf(f2.y); t1[2]=f2bf(f2.z); t1[3]=f2bf(f2.w);
            t1[4]=f2bf(f3.x); t1[5]=f2bf(f3.y); t1[6]=f2bf(f3.z); t1[7]=f2bf(f3.w);
            *(short8*)dst = t0; *(short8*)(dst + 8) = t1;
        }
        __syncthreads();

        short8 af[4], bfr[4];
#pragma unroll
        for (int i = 0; i < 4; i++)
            af[i] = *(const short8*)&As[(wm + i * 16 + l15) * 40 + quad * 8];
#pragma unroll
        for (int j = 0; j < 4; j++)
            bfr[j] = *(const short8*)&Bs[(wn + j * 16 + l15) * 40 + quad * 8];
#pragma unroll
        for (int i = 0; i < 4; i++)
#pragma unroll
            for (int j = 0; j < 4; j++)
                acc[i][j] = __builtin_amdgcn_mfma_f32_16x16x32_bf16(af[i], bfr[j], acc[i][j], 0, 0, 0);
    }

#pragma unroll
    for (int i = 0; i < 4; i++)
#pragma unroll
        for (int j = 0; j < 4; j++) {
            const int col = bn + wn + j * 16 + l15;
            const int row0 = bm + wm + i * 16 + quad * 4;
#pragma unroll
            for (int r = 0; r < 4; r++)
                out[(size_t)(row0 + r) * ldc + col] = acc[i][j][r];
        }
}

// ---------------------------------------------------------------------------
// Flash attention v12 (round-6 proven, UNCHANGED): staging-free, coalesced
// fragment-major K/V loads, 1024 blocks x 4 waves, balanced qt map.
// ---------------------------------------------------------------------------
__global__ __launch_bounds__(256, 4) void flash_kernel(
    const short* __restrict__ qh, const short* __restrict__ khF,
    const short* __restrict__ vF, short* __restrict__ attn)
{
    __shared__ float Os[4][16][128];   // per-wave O partials (32 KB)
    __shared__ short Ps[4][16 * 40];   // per-wave P scratch (5 KB)
    __shared__ float Lp[4][16];        // per-wave row sums

    const int id = blockIdx.x;         // 0..1023
    const int hb = id & 7;
    const int b = hb & 1;
    const int h = hb >> 1;
    const int s = id >> 3;             // 0..127
    const int m = s & 31;
    const int g = s >> 5;              // 0..3
    const int base = (g >> 1) * 32 + m;            // {m, 32+m}
    const int qt = (g & 1) ? (127 - base) : base;  // bijective onto 0..127
    const int tid = threadIdx.x;
    const int w = tid >> 6;
    const int lane = tid & 63;
    const int l15 = lane & 15;
    const int quad = lane >> 4;

    const float scale = 0.08838834764831845f;
    const float MFIX = 24.0f;

    const int q0 = qt * 16;
    const int ntiles = (q0 + 47) >> 5;

    const short* qrow = qh + (size_t)(b * 2048 + q0 + l15) * 512 + h * 128;
    short8 aq[4];
#pragma unroll
    for (int kk = 0; kk < 4; kk++)
        aq[kk] = *(const short8*)&qrow[kk * 32 + quad * 8];

    const short* kfb = khF + (size_t)(b * 4 + h) * 262144 + lane * 8;
    const short* vfb = vF  + (size_t)(b * 4 + h) * 262144 + lane * 8;

    f32x4 o[8];
#pragma unroll
    for (int dt = 0; dt < 8; dt++) o[dt] = zero4();
    float lsum[4] = {0.f, 0.f, 0.f, 0.f};

    short* pw = &Ps[w][0];

    for (int t = w; t < ntiles; t += 4) {
        const int kb0 = t * 32;
        const short* kt_ = kfb + t * 4096;
        const short* vt_ = vfb + t * 4096;

        // ---- S = Q K^T (16q x 32k); K frags = coalesced global loads ----
        f32x4 sc[2];
#pragma unroll
        for (int ct = 0; ct < 2; ct++) {
            sc[ct] = zero4();
#pragma unroll
            for (int kk = 0; kk < 4; kk++) {
                short8 bk = *(const short8*)&kt_[ct * 2048 + kk * 512];
                sc[ct] = __builtin_amdgcn_mfma_f32_16x16x32_bf16(aq[kk], bk, sc[ct], 0, 0, 0);
            }
        }

        // ---- V frags = coalesced global loads ----
        short8 bv[8];
#pragma unroll
        for (int dt = 0; dt < 8; dt++)
            bv[dt] = *(const short8*)&vt_[dt * 512];

        // ---- fixed-max softmax: p = exp(s*scale - M), masked -> 0 ----
        const int rbase = q0 + quad * 4;
        float p[2][4];
#pragma unroll
        for (int ct = 0; ct < 2; ct++) {
            const int kcol = kb0 + ct * 16 + l15;
#pragma unroll
            for (int r = 0; r < 4; r++) {
                const float e = __expf(sc[ct][r] * scale - MFIX);
                const float pv = (kcol > rbase + r) ? 0.0f : e;
                p[ct][r] = pv;
                lsum[r] += pv;
            }
        }

        // ---- P -> per-wave LDS (A-operand layout); intra-wave ----
#pragma unroll
        for (int ct = 0; ct < 2; ct++)
#pragma unroll
            for (int r = 0; r < 4; r++)
                pw[(quad * 4 + r) * 40 + ct * 16 + l15] = f2bf(p[ct][r]);
        short8 ap = *(const short8*)&pw[l15 * 40 + quad * 8];

        // ---- O += P V ----
#pragma unroll
        for (int dt = 0; dt < 8; dt++)
            o[dt] = __builtin_amdgcn_mfma_f32_16x16x32_bf16(ap, bv[dt], o[dt], 0, 0, 0);
    }

    // ---- merge 4 waves: plain sums (common fixed max) ----
#pragma unroll
    for (int r = 0; r < 4; r++) {
        float vsum = lsum[r];
#pragma unroll
        for (int off = 1; off < 16; off <<= 1)
            vsum += __shfl_xor(vsum, off, 64);
        if (l15 == 0) Lp[w][quad * 4 + r] = vsum;
#pragma unroll
        for (int dt = 0; dt < 8; dt++)
            Os[w][quad * 4 + r][dt * 16 + l15] = o[dt][r];
    }
    __syncthreads();

    {
        const int row = tid >> 4;
        const int d0 = (tid & 15) * 8;
        const float L = Lp[0][row] + Lp[1][row] + Lp[2][row] + Lp[3][row];
        const float rL = 1.0f / L;
        short8 ov;
#pragma unroll
        for (int j = 0; j < 8; j++) {
            const float osum = Os[0][row][d0 + j] + Os[1][row][d0 + j]
                             + Os[2][row][d0 + j] + Os[3][row][d0 + j];
            ov[j] = f2bf(osum * rL);
        }
        *(short8*)&attn[(size_t)(b * 2048 + q0 + row) * 512 + h * 128 + d0] = ov;
    }
}

extern "C" void kernel_launch(void* const* d_in, const int* in_sizes, int n_in,
                              void* d_out, int out_size, void* d_ws, size_t ws_size,
                              hipStream_t stream) {
    const float* q  = (const float*)d_in[0];
    const float* k  = (const float*)d_in[1];
    const float* v  = (const float*)d_in[2];
    const float* Wq = (const float*)d_in[3];
    const float* Wk = (const float*)d_in[4];
    const float* Wv = (const float*)d_in[5];
    const float* Wo = (const float*)d_in[6];
    float* out = (float*)d_out;

    const size_t MB = 1024 * 1024;
    // ws (16 MB):
    char* ws = (char*)d_ws;
    short* qh   = (short*)(ws);               // [4096,512] bf16 row-major, 4 MB
    short* khF  = (short*)(ws + 4 * MB);      // fragment-major K, 4 MB
    short* vF   = (short*)(ws + 8 * MB);      // fragment-major V, 4 MB
    short* Wqb  = (short*)(ws + 12 * MB);     // frag-major Wq[0:512,:], dead after proj
    short* Wkb  = (short*)(ws + 13 * MB + 512 * 1024);
    short* attn = (short*)(ws + 12 * MB);     // flash writes over dead Wqb/Wkb
    // d_out (24 MB) as scratch until outproj:
    short* qb   = (short*)d_out;                      // frag-major q, dead after proj
    short* kb   = (short*)((char*)d_out + 12 * MB);   // frag-major k, dead after proj

    // 1) fp32 -> bf16, fragment-major
    convertA_kernel<<<dim3(3072, 1, 4), 256, 0, stream>>>(q, k, Wq, Wk, qb, kb, Wqb, Wkb);
    // 2) projections: z0/z1 direct-fragment GEMM (no LDS), z2 fp32 core
    proj_kernel<<<dim3(4, 64, 3), 256, 0, stream>>>(qb, kb, v, Wqb, Wkb, Wv, qh, khF, vF);
    // 3) flash attention v12 (staging-free, coalesced fragment loads)
    flash_kernel<<<dim3(1024, 1, 1), 256, 0, stream>>>(qh, khF, vF, attn);
    // 4) output projection (convertB fused: B staged fp32->bf16)
    outproj_kernel<<<dim3(12, 32, 1), 256, 0, stream>>>(attn, Wo, out);
}

// Round 8
// 223.851 us; speedup vs baseline: 1.0354x; 1.0354x over previous
//
#include <hip/hip_runtime.h>
#include <hip/hip_bf16.h>

typedef __attribute__((ext_vector_type(8))) short short8;
typedef __attribute__((ext_vector_type(4))) short short4v;
typedef __attribute__((ext_vector_type(4))) float f32x4;

__device__ __forceinline__ short f2bf(float f) {
    union { float f; unsigned u; } v; v.f = f;
    unsigned r = (v.u + 0x7fffu + ((v.u >> 16) & 1u)) >> 16;
    return (short)r;
}
__device__ __forceinline__ float bf2f(short s) {
    union { unsigned u; float f; } v; v.u = ((unsigned)(unsigned short)s) << 16;
    return v.f;
}
__device__ __forceinline__ f32x4 zero4() { f32x4 z = {0.f, 0.f, 0.f, 0.f}; return z; }

// ---------------------------------------------------------------------------
// convertA v2 (round-7 proven): fp32 -> bf16 in MFMA-FRAGMENT-MAJOR layout.
// Fragment = 16 rows x 32 k-cols; frag idx f = (row>>4)*48 + (k>>5);
// elem (lane*8+e) <-> (row = l15, k = quad*8+e).
// z=0: qbF  z=1: kbF  z=2: WqbF (rows 0..511)  z=3: WkbF
// ---------------------------------------------------------------------------
__global__ __launch_bounds__(256) void convertA_kernel(
    const float* __restrict__ q, const float* __restrict__ k,
    const float* __restrict__ Wq, const float* __restrict__ Wk,
    short* __restrict__ qb, short* __restrict__ kb,
    short* __restrict__ Wqb, short* __restrict__ Wkb)
{
    const int tid = threadIdx.x;
    const int w = tid >> 6;
    const int lane = tid & 63;
    const int l15 = lane & 15;
    const int quad = lane >> 4;
    const int f = blockIdx.x * 4 + w;          // fragment index (wave-uniform)
    const float* src; short* dst; int nfrag;
    switch (blockIdx.z) {
    case 0:  nfrag = 12288; src = q;  dst = qb;  break;   // 256 r16 x 48 kt
    case 1:  nfrag = 12288; src = k;  dst = kb;  break;
    case 2:  nfrag = 1536;  src = Wq; dst = Wqb; break;   // 32 r16 x 48 kt
    default: nfrag = 1536;  src = Wk; dst = Wkb; break;
    }
    if (f >= nfrag) return;
    const int r16 = f / 48;
    const int kt  = f - r16 * 48;
    const float* s = src + (size_t)(r16 * 16 + l15) * 1536 + kt * 32 + quad * 8;
    const float4 a = ((const float4*)s)[0];
    const float4 b = ((const float4*)s)[1];
    short8 o;
    o[0]=f2bf(a.x); o[1]=f2bf(a.y); o[2]=f2bf(a.z); o[3]=f2bf(a.w);
    o[4]=f2bf(b.x); o[5]=f2bf(b.y); o[6]=f2bf(b.z); o[7]=f2bf(b.w);
    *(short8*)(dst + (size_t)f * 512 + lane * 8) = o;
}

// ---------------------------------------------------------------------------
// proj z0/z1 v3: direct-fragment GEMM + XCD-affinity tile map + register
// double-buffer prefetch.
// Round-7 post-mortem: bm=flat>>3 put the 8 bn-tiles of each A-panel on 8
// DIFFERENT XCDs (round-robin xcd = lin%8) -> A fetched 8x from HBM (FETCH
// 120 MB). Fix: c=flat&7, t=flat>>3, bm=(c*4+(t>>3)), bn=t&7 -> XCD c owns
// A-panels 4c..4c+3 entirely; A read once, L2-resident (1.6 MB A + 1.5 MB B
// < 4 MB L2/XCD). Prefetch: named bufA/bufB, kt+=2 (compile-time indices,
// rule #20) so next step's 6 loads issue under current 8 MFMAs.
// ---------------------------------------------------------------------------
template<int MODE>
__device__ __forceinline__ void gemm_frag_direct(
    const short* __restrict__ Af, const short* __restrict__ Bf, short* __restrict__ Cp)
{
    const int flat = blockIdx.x + (blockIdx.y << 2);   // 0..255
    const int c = flat & 7;
    const int t = flat >> 3;
    const int bm = (c * 4 + (t >> 3)) * 128;
    const int bn = (t & 7) * 64;
    const int tid = threadIdx.x;
    const int w = tid >> 6;
    const int lane = tid & 63;
    const int l15 = lane & 15;
    const int quad = lane >> 4;
    const int wm = (w >> 1) * 64;
    const int wn = (w & 1) * 32;

    const short* ab = Af + (size_t)((bm + wm) >> 4) * 24576 + lane * 8;
    const short* bb = Bf + (size_t)((bn + wn) >> 4) * 24576 + lane * 8;

    f32x4 acc[4][2];
#pragma unroll
    for (int i = 0; i < 4; i++)
#pragma unroll
        for (int j = 0; j < 2; j++) acc[i][j] = zero4();

    short8 aA[4], bA[2], aB[4], bB[2];
#pragma unroll
    for (int i = 0; i < 4; i++) aA[i] = *(const short8*)(ab + i * 24576);
#pragma unroll
    for (int j = 0; j < 2; j++) bA[j] = *(const short8*)(bb + j * 24576);

    for (int kt = 0; kt < 48; kt += 2) {
        // prefetch kt+1 into B-buffer (kt+1 <= 47 always)
#pragma unroll
        for (int i = 0; i < 4; i++) aB[i] = *(const short8*)(ab + i * 24576 + (kt + 1) * 512);
#pragma unroll
        for (int j = 0; j < 2; j++) bB[j] = *(const short8*)(bb + j * 24576 + (kt + 1) * 512);
        // compute kt from A-buffer
#pragma unroll
        for (int i = 0; i < 4; i++)
#pragma unroll
            for (int j = 0; j < 2; j++)
                acc[i][j] = __builtin_amdgcn_mfma_f32_16x16x32_bf16(aA[i], bA[j], acc[i][j], 0, 0, 0);
        // prefetch kt+2 into A-buffer
        if (kt + 2 < 48) {
#pragma unroll
            for (int i = 0; i < 4; i++) aA[i] = *(const short8*)(ab + i * 24576 + (kt + 2) * 512);
#pragma unroll
            for (int j = 0; j < 2; j++) bA[j] = *(const short8*)(bb + j * 24576 + (kt + 2) * 512);
        }
        // compute kt+1 from B-buffer
#pragma unroll
        for (int i = 0; i < 4; i++)
#pragma unroll
            for (int j = 0; j < 2; j++)
                acc[i][j] = __builtin_amdgcn_mfma_f32_16x16x32_bf16(aB[i], bB[j], acc[i][j], 0, 0, 0);
    }

#pragma unroll
    for (int i = 0; i < 4; i++)
#pragma unroll
        for (int j = 0; j < 2; j++) {
            const int col = bn + wn + j * 16 + l15;
            const int row0 = bm + wm + i * 16 + quad * 4;
            const int pairi = (col & 127) >> 1;   // same for both lanes of a pair
            const float freq = exp2f(-(float)(2 * pairi) * (13.287712379549449f / 128.0f));
            const bool even = (l15 & 1) == 0;
#pragma unroll
            for (int r = 0; r < 4; r++) {
                const float own = acc[i][j][r];
                const float other = __shfl_xor(own, 1, 64);
                const float pos = (float)((row0 + r) & 2047);
                const float ang = pos * freq;
                const float n = rintf(ang * 0.15915494309189535f);
                const float rr = (ang - n * 6.28125f) - n * 1.9353071795864769e-3f;
                float s, c2;
                __sincosf(rr, &s, &c2);
                const float x1 = even ? own : other;
                const float x2 = even ? other : own;
                const float res = even ? (x1 * c2 - x2 * s) : (x1 * s + x2 * c2);
                if constexpr (MODE == 1) {
                    Cp[(size_t)(row0 + r) * 512 + col] = f2bf(res);
                } else {
                    const int seq = row0 + r;
                    const int b_ = seq >> 11;
                    const int s2 = seq & 2047;
                    Cp[(size_t)(b_ * 4 + (col >> 7)) * 262144 + (s2 >> 5) * 4096
                       + ((s2 >> 4) & 1) * 2048 + ((col >> 5) & 3) * 512
                       + ((col >> 3) & 3) * 128 + (s2 & 15) * 8 + (col & 7)] = f2bf(res);
                }
            }
        }
}

// ---------------------------------------------------------------------------
// fp32-input GEMM, BM=64 BN=128 BK=32 (proven core), MFMA-fragment-major V
// store (vF) for coalesced flash V-operand loads. UNCHANGED from round 6.
// ---------------------------------------------------------------------------
__device__ __forceinline__ void gemm_f32T_vF(
    const float* __restrict__ A, const float* __restrict__ Bw, short* __restrict__ Cp,
    int K, int lda, int ldb, short* As, short* Bs)
{
    const int bm = blockIdx.y * 64;
    const int bn = blockIdx.x * 128;
    const int tid = threadIdx.x;
    const int w = tid >> 6;
    const int lane = tid & 63;
    const int l15 = lane & 15;
    const int quad = lane >> 4;
    const int wm = (w >> 1) * 32;
    const int wn = (w & 1) * 64;
    const int srA = tid >> 2;
    const int scA = (tid & 3) * 8;
    const int srB = tid >> 1;
    const int scB = (tid & 1) * 16;

    f32x4 acc[2][4];
#pragma unroll
    for (int i = 0; i < 2; i++)
#pragma unroll
        for (int j = 0; j < 4; j++) acc[i][j] = zero4();

    for (int k0 = 0; k0 < K; k0 += 32) {
        __syncthreads();
        {
            const float* src = A + (size_t)(bm + srA) * lda + k0 + scA;
            short* dst = &As[srA * 40 + scA];
            const float4* s4 = (const float4*)src;
            float4 f0 = s4[0], f1 = s4[1];
            short8 t0;
            t0[0]=f2bf(f0.x); t0[1]=f2bf(f0.y); t0[2]=f2bf(f0.z); t0[3]=f2bf(f0.w);
            t0[4]=f2bf(f1.x); t0[5]=f2bf(f1.y); t0[6]=f2bf(f1.z); t0[7]=f2bf(f1.w);
            *(short8*)dst = t0;
        }
        {
            const float* src = Bw + (size_t)(bn + srB) * ldb + k0 + scB;
            short* dst = &Bs[srB * 40 + scB];
            const float4* s4 = (const float4*)src;
            float4 f0 = s4[0], f1 = s4[1], f2 = s4[2], f3 = s4[3];
            short8 t0, t1;
            t0[0]=f2bf(f0.x); t0[1]=f2bf(f0.y); t0[2]=f2bf(f0.z); t0[3]=f2bf(f0.w);
            t0[4]=f2bf(f1.x); t0[5]=f2bf(f1.y); t0[6]=f2bf(f1.z); t0[7]=f2bf(f1.w);
            t1[0]=f2bf(f2.x); t1[1]=f2bf(f2.y); t1[2]=f2bf(f2.z); t1[3]=f2bf(f2.w);
            t1[4]=f2bf(f3.x); t1[5]=f2bf(f3.y); t1[6]=f2bf(f3.z); t1[7]=f2bf(f3.w);
            *(short8*)dst = t0; *(short8*)(dst + 8) = t1;
        }
        __syncthreads();

        short8 af[2], bfr[4];
#pragma unroll
        for (int i = 0; i < 2; i++)
            af[i] = *(const short8*)&As[(wm + i * 16 + l15) * 40 + quad * 8];
#pragma unroll
        for (int j = 0; j < 4; j++)
            bfr[j] = *(const short8*)&Bs[(wn + j * 16 + l15) * 40 + quad * 8];
#pragma unroll
        for (int i = 0; i < 2; i++)
#pragma unroll
            for (int j = 0; j < 4; j++)
                acc[i][j] = __builtin_amdgcn_mfma_f32_16x16x32_bf16(af[i], bfr[j], acc[i][j], 0, 0, 0);
    }

#pragma unroll
    for (int i = 0; i < 2; i++)
#pragma unroll
        for (int j = 0; j < 4; j++) {
            const int col = bn + wn + j * 16 + l15;     // d feature 0..511
            const int row0 = bm + wm + i * 16 + quad * 4; // kv seq 0..4095
            const int b_ = row0 >> 11;
            const int s2 = row0 & 2047;
            short4v p;
#pragma unroll
            for (int r = 0; r < 4; r++) p[r] = f2bf(acc[i][j][r]);
            const size_t addr = (size_t)(b_ * 4 + (col >> 7)) * 262144 + (s2 >> 5) * 4096
                              + ((col >> 4) & 7) * 512 + ((s2 >> 3) & 3) * 128
                              + (col & 15) * 8 + (s2 & 7);
            *(short4v*)&Cp[addr] = p;
        }
}

// z=0: qh direct-frag (XCD-affine); z=1: khF likewise; z=2: vF fp32 core.
// Grid (4, 64, 3) = 768 blocks = 3/CU.
__global__ __launch_bounds__(256) void proj_kernel(
    const short* __restrict__ qb, const short* __restrict__ kb, const float* __restrict__ v,
    const short* __restrict__ Wqb, const short* __restrict__ Wkb, const float* __restrict__ Wv,
    short* __restrict__ qh, short* __restrict__ khF, short* __restrict__ vF)
{
    __shared__ short smem[12288];   // used by z2 only
    switch (blockIdx.z) {
    case 0:  gemm_frag_direct<1>(qb, Wqb, qh); break;
    case 1:  gemm_frag_direct<2>(kb, Wkb, khF); break;
    default: gemm_f32T_vF(v + 512, Wv, vF, 512, 1536, 512, smem, smem + 2560); break;
    }
}

// out[4096,1536] = attn[4096,512] @ Wo[:, :512]^T — convertB fused (B fp32 staging)
__global__ __launch_bounds__(256) void outproj_kernel(
    const short* __restrict__ attn, const float* __restrict__ Wo, float* __restrict__ out)
{
    __shared__ short smem[2][5120];
    const int bm = blockIdx.y * 128;
    const int bn = blockIdx.x * 128;
    const int tid = threadIdx.x;
    const int w = tid >> 6;
    const int lane = tid & 63;
    const int l15 = lane & 15;
    const int quad = lane >> 4;
    const int wm = (w >> 1) * 64;
    const int wn = (w & 1) * 64;
    const int srow = tid >> 1;
    const int scol = (tid & 1) * 16;
    short* As = smem[0];
    short* Bs = smem[1];
    const int K = 512, lda = 512, ldb = 1536, ldc = 1536;

    f32x4 acc[4][4];
#pragma unroll
    for (int i = 0; i < 4; i++)
#pragma unroll
        for (int j = 0; j < 4; j++) acc[i][j] = zero4();

    for (int k0 = 0; k0 < K; k0 += 32) {
        __syncthreads();
        {
            const short* src = attn + (size_t)(bm + srow) * lda + k0 + scol;
            short* dst = &As[srow * 40 + scol];
            const uint4* s4 = (const uint4*)src;
            uint4 a = s4[0], b = s4[1];
            *(uint4*)dst = a; *(uint4*)(dst + 8) = b;
        }
        {
            const float* src = Wo + (size_t)(bn + srow) * ldb + k0 + scol;
            short* dst = &Bs[srow * 40 + scol];
            const float4* s4 = (const float4*)src;
            float4 f0 = s4[0], f1 = s4[1], f2 = s4[2], f3 = s4[3];
            short8 t0, t1;
            t0[0]=f2bf(f0.x); t0[1]=f2bf(f0.y); t0[2]=f2bf(f0.z); t0[3]=f2bf(f0.w);
            t0[4]=f2bf(f1.x); t0[5]=f2bf(f1.y); t0[6]=f2bf(f1.z); t0[7]=f2bf(f1.w);
            t1[0]=f2bf(f2.x); t1[1]=f2bf(f2.y); t1[2]=f2bf(f2.z); t1[3]=f2bf(f2.w);
            t1[4]=f2bf(f3.x); t1[5]=f2bf(f3.y); t1[6]=f2bf(f3.z); t1[7]=f2bf(f3.w);
            *(short8*)dst = t0; *(short8*)(dst + 8) = t1;
        }
        __syncthreads();

        short8 af[4], bfr[4];
#pragma unroll
        for (int i = 0; i < 4; i++)
            af[i] = *(const short8*)&As[(wm + i * 16 + l15) * 40 + quad * 8];
#pragma unroll
        for (int j = 0; j < 4; j++)
            bfr[j] = *(const short8*)&Bs[(wn + j * 16 + l15) * 40 + quad * 8];
#pragma unroll
        for (int i = 0; i < 4; i++)
#pragma unroll
            for (int j = 0; j < 4; j++)
                acc[i][j] = __builtin_amdgcn_mfma_f32_16x16x32_bf16(af[i], bfr[j], acc[i][j], 0, 0, 0);
    }

#pragma unroll
    for (int i = 0; i < 4; i++)
#pragma unroll
        for (int j = 0; j < 4; j++) {
            const int col = bn + wn + j * 16 + l15;
            const int row0 = bm + wm + i * 16 + quad * 4;
#pragma unroll
            for (int r = 0; r < 4; r++)
                out[(size_t)(row0 + r) * ldc + col] = acc[i][j][r];
        }
}

// ---------------------------------------------------------------------------
// Flash attention v12 (round-6 proven, UNCHANGED): staging-free, coalesced
// fragment-major K/V loads, 1024 blocks x 4 waves, balanced qt map.
// ---------------------------------------------------------------------------
__global__ __launch_bounds__(256, 4) void flash_kernel(
    const short* __restrict__ qh, const short* __restrict__ khF,
    const short* __restrict__ vF, short* __restrict__ attn)
{
    __shared__ float Os[4][16][128];   // per-wave O partials (32 KB)
    __shared__ short Ps[4][16 * 40];   // per-wave P scratch (5 KB)
    __shared__ float Lp[4][16];        // per-wave row sums

    const int id = blockIdx.x;         // 0..1023
    const int hb = id & 7;
    const int b = hb & 1;
    const int h = hb >> 1;
    const int s = id >> 3;             // 0..127
    const int m = s & 31;
    const int g = s >> 5;              // 0..3
    const int base = (g >> 1) * 32 + m;            // {m, 32+m}
    const int qt = (g & 1) ? (127 - base) : base;  // bijective onto 0..127
    const int tid = threadIdx.x;
    const int w = tid >> 6;
    const int lane = tid & 63;
    const int l15 = lane & 15;
    const int quad = lane >> 4;

    const float scale = 0.08838834764831845f;
    const float MFIX = 24.0f;

    const int q0 = qt * 16;
    const int ntiles = (q0 + 47) >> 5;

    const short* qrow = qh + (size_t)(b * 2048 + q0 + l15) * 512 + h * 128;
    short8 aq[4];
#pragma unroll
    for (int kk = 0; kk < 4; kk++)
        aq[kk] = *(const short8*)&qrow[kk * 32 + quad * 8];

    const short* kfb = khF + (size_t)(b * 4 + h) * 262144 + lane * 8;
    const short* vfb = vF  + (size_t)(b * 4 + h) * 262144 + lane * 8;

    f32x4 o[8];
#pragma unroll
    for (int dt = 0; dt < 8; dt++) o[dt] = zero4();
    float lsum[4] = {0.f, 0.f, 0.f, 0.f};

    short* pw = &Ps[w][0];

    for (int t = w; t < ntiles; t += 4) {
        const int kb0 = t * 32;
        const short* kt_ = kfb + t * 4096;
        const short* vt_ = vfb + t * 4096;

        // ---- S = Q K^T (16q x 32k); K frags = coalesced global loads ----
        f32x4 sc[2];
#pragma unroll
        for (int ct = 0; ct < 2; ct++) {
            sc[ct] = zero4();
#pragma unroll
            for (int kk = 0; kk < 4; kk++) {
                short8 bk = *(const short8*)&kt_[ct * 2048 + kk * 512];
                sc[ct] = __builtin_amdgcn_mfma_f32_16x16x32_bf16(aq[kk], bk, sc[ct], 0, 0, 0);
            }
        }

        // ---- V frags = coalesced global loads ----
        short8 bv[8];
#pragma unroll
        for (int dt = 0; dt < 8; dt++)
            bv[dt] = *(const short8*)&vt_[dt * 512];

        // ---- fixed-max softmax: p = exp(s*scale - M), masked -> 0 ----
        const int rbase = q0 + quad * 4;
        float p[2][4];
#pragma unroll
        for (int ct = 0; ct < 2; ct++) {
            const int kcol = kb0 + ct * 16 + l15;
#pragma unroll
            for (int r = 0; r < 4; r++) {
                const float e = __expf(sc[ct][r] * scale - MFIX);
                const float pv = (kcol > rbase + r) ? 0.0f : e;
                p[ct][r] = pv;
                lsum[r] += pv;
            }
        }

        // ---- P -> per-wave LDS (A-operand layout); intra-wave ----
#pragma unroll
        for (int ct = 0; ct < 2; ct++)
#pragma unroll
            for (int r = 0; r < 4; r++)
                pw[(quad * 4 + r) * 40 + ct * 16 + l15] = f2bf(p[ct][r]);
        short8 ap = *(const short8*)&pw[l15 * 40 + quad * 8];

        // ---- O += P V ----
#pragma unroll
        for (int dt = 0; dt < 8; dt++)
            o[dt] = __builtin_amdgcn_mfma_f32_16x16x32_bf16(ap, bv[dt], o[dt], 0, 0, 0);
    }

    // ---- merge 4 waves: plain sums (common fixed max) ----
#pragma unroll
    for (int r = 0; r < 4; r++) {
        float vsum = lsum[r];
#pragma unroll
        for (int off = 1; off < 16; off <<= 1)
            vsum += __shfl_xor(vsum, off, 64);
        if (l15 == 0) Lp[w][quad * 4 + r] = vsum;
#pragma unroll
        for (int dt = 0; dt < 8; dt++)
            Os[w][quad * 4 + r][dt * 16 + l15] = o[dt][r];
    }
    __syncthreads();

    {
        const int row = tid >> 4;
        const int d0 = (tid & 15) * 8;
        const float L = Lp[0][row] + Lp[1][row] + Lp[2][row] + Lp[3][row];
        const float rL = 1.0f / L;
        short8 ov;
#pragma unroll
        for (int j = 0; j < 8; j++) {
            const float osum = Os[0][row][d0 + j] + Os[1][row][d0 + j]
                             + Os[2][row][d0 + j] + Os[3][row][d0 + j];
            ov[j] = f2bf(osum * rL);
        }
        *(short8*)&attn[(size_t)(b * 2048 + q0 + row) * 512 + h * 128 + d0] = ov;
    }
}

extern "C" void kernel_launch(void* const* d_in, const int* in_sizes, int n_in,
                              void* d_out, int out_size, void* d_ws, size_t ws_size,
                              hipStream_t stream) {
    const float* q  = (const float*)d_in[0];
    const float* k  = (const float*)d_in[1];
    const float* v  = (const float*)d_in[2];
    const float* Wq = (const float*)d_in[3];
    const float* Wk = (const float*)d_in[4];
    const float* Wv = (const float*)d_in[5];
    const float* Wo = (const float*)d_in[6];
    float* out = (float*)d_out;

    const size_t MB = 1024 * 1024;
    // ws (16 MB):
    char* ws = (char*)d_ws;
    short* qh   = (short*)(ws);               // [4096,512] bf16 row-major, 4 MB
    short* khF  = (short*)(ws + 4 * MB);      // fragment-major K, 4 MB
    short* vF   = (short*)(ws + 8 * MB);      // fragment-major V, 4 MB
    short* Wqb  = (short*)(ws + 12 * MB);     // frag-major Wq[0:512,:], dead after proj
    short* Wkb  = (short*)(ws + 13 * MB + 512 * 1024);
    short* attn = (short*)(ws + 12 * MB);     // flash writes over dead Wqb/Wkb
    // d_out (24 MB) as scratch until outproj:
    short* qb   = (short*)d_out;                      // frag-major q, dead after proj
    short* kb   = (short*)((char*)d_out + 12 * MB);   // frag-major k, dead after proj

    // 1) fp32 -> bf16, fragment-major
    convertA_kernel<<<dim3(3072, 1, 4), 256, 0, stream>>>(q, k, Wq, Wk, qb, kb, Wqb, Wkb);
    // 2) projections: z0/z1 direct-fragment GEMM (XCD-affine + prefetch), z2 fp32 core
    proj_kernel<<<dim3(4, 64, 3), 256, 0, stream>>>(qb, kb, v, Wqb, Wkb, Wv, qh, khF, vF);
    // 3) flash attention v12 (staging-free, coalesced fragment loads)
    flash_kernel<<<dim3(1024, 1, 1), 256, 0, stream>>>(qh, khF, vF, attn);
    // 4) output projection (convertB fused: B staged fp32->bf16)
    outproj_kernel<<<dim3(12, 32, 1), 256, 0, stream>>>(attn, Wo, out);
}

// Round 9
// 215.223 us; speedup vs baseline: 1.0770x; 1.0401x over previous
//
#include <hip/hip_runtime.h>
#include <hip/hip_bf16.h>

typedef __attribute__((ext_vector_type(8))) short short8;
typedef __attribute__((ext_vector_type(4))) short short4v;
typedef __attribute__((ext_vector_type(4))) float f32x4;

__device__ __forceinline__ short f2bf(float f) {
    union { float f; unsigned u; } v; v.f = f;
    unsigned r = (v.u + 0x7fffu + ((v.u >> 16) & 1u)) >> 16;
    return (short)r;
}
__device__ __forceinline__ float bf2f(short s) {
    union { unsigned u; float f; } v; v.u = ((unsigned)(unsigned short)s) << 16;
    return v.f;
}
__device__ __forceinline__ f32x4 zero4() { f32x4 z = {0.f, 0.f, 0.f, 0.f}; return z; }

// ---------------------------------------------------------------------------
// convertA v2 (round-7 proven): fp32 -> bf16 in MFMA-FRAGMENT-MAJOR layout.
// Fragment = 16 rows x 32 k-cols; frag idx f = (row>>4)*48 + (k>>5);
// elem (lane*8+e) <-> (row = l15, k = quad*8+e).
// z=0: qbF  z=1: kbF  z=2: WqbF (rows 0..511)  z=3: WkbF
// ---------------------------------------------------------------------------
__global__ __launch_bounds__(256) void convertA_kernel(
    const float* __restrict__ q, const float* __restrict__ k,
    const float* __restrict__ Wq, const float* __restrict__ Wk,
    short* __restrict__ qb, short* __restrict__ kb,
    short* __restrict__ Wqb, short* __restrict__ Wkb)
{
    const int tid = threadIdx.x;
    const int w = tid >> 6;
    const int lane = tid & 63;
    const int l15 = lane & 15;
    const int quad = lane >> 4;
    const int f = blockIdx.x * 4 + w;          // fragment index (wave-uniform)
    const float* src; short* dst; int nfrag;
    switch (blockIdx.z) {
    case 0:  nfrag = 12288; src = q;  dst = qb;  break;   // 256 r16 x 48 kt
    case 1:  nfrag = 12288; src = k;  dst = kb;  break;
    case 2:  nfrag = 1536;  src = Wq; dst = Wqb; break;   // 32 r16 x 48 kt
    default: nfrag = 1536;  src = Wk; dst = Wkb; break;
    }
    if (f >= nfrag) return;
    const int r16 = f / 48;
    const int kt  = f - r16 * 48;
    const float* s = src + (size_t)(r16 * 16 + l15) * 1536 + kt * 32 + quad * 8;
    const float4 a = ((const float4*)s)[0];
    const float4 b = ((const float4*)s)[1];
    short8 o;
    o[0]=f2bf(a.x); o[1]=f2bf(a.y); o[2]=f2bf(a.z); o[3]=f2bf(a.w);
    o[4]=f2bf(b.x); o[5]=f2bf(b.y); o[6]=f2bf(b.z); o[7]=f2bf(b.w);
    *(short8*)(dst + (size_t)f * 512 + lane * 8) = o;
}

// ---------------------------------------------------------------------------
// proj z0/z1 v3 (round-8 proven): direct-fragment GEMM + XCD-affinity tile
// map + register double-buffer prefetch. A panels owned per-XCD -> A read
// once from HBM, L2-resident.
// ---------------------------------------------------------------------------
template<int MODE>
__device__ __forceinline__ void gemm_frag_direct(
    const short* __restrict__ Af, const short* __restrict__ Bf, short* __restrict__ Cp)
{
    const int flat = blockIdx.x + (blockIdx.y << 2);   // 0..255
    const int c = flat & 7;
    const int t = flat >> 3;
    const int bm = (c * 4 + (t >> 3)) * 128;
    const int bn = (t & 7) * 64;
    const int tid = threadIdx.x;
    const int w = tid >> 6;
    const int lane = tid & 63;
    const int l15 = lane & 15;
    const int quad = lane >> 4;
    const int wm = (w >> 1) * 64;
    const int wn = (w & 1) * 32;

    const short* ab = Af + (size_t)((bm + wm) >> 4) * 24576 + lane * 8;
    const short* bb = Bf + (size_t)((bn + wn) >> 4) * 24576 + lane * 8;

    f32x4 acc[4][2];
#pragma unroll
    for (int i = 0; i < 4; i++)
#pragma unroll
        for (int j = 0; j < 2; j++) acc[i][j] = zero4();

    short8 aA[4], bA[2], aB[4], bB[2];
#pragma unroll
    for (int i = 0; i < 4; i++) aA[i] = *(const short8*)(ab + i * 24576);
#pragma unroll
    for (int j = 0; j < 2; j++) bA[j] = *(const short8*)(bb + j * 24576);

    for (int kt = 0; kt < 48; kt += 2) {
        // prefetch kt+1 into B-buffer (kt+1 <= 47 always)
#pragma unroll
        for (int i = 0; i < 4; i++) aB[i] = *(const short8*)(ab + i * 24576 + (kt + 1) * 512);
#pragma unroll
        for (int j = 0; j < 2; j++) bB[j] = *(const short8*)(bb + j * 24576 + (kt + 1) * 512);
        // compute kt from A-buffer
#pragma unroll
        for (int i = 0; i < 4; i++)
#pragma unroll
            for (int j = 0; j < 2; j++)
                acc[i][j] = __builtin_amdgcn_mfma_f32_16x16x32_bf16(aA[i], bA[j], acc[i][j], 0, 0, 0);
        // prefetch kt+2 into A-buffer
        if (kt + 2 < 48) {
#pragma unroll
            for (int i = 0; i < 4; i++) aA[i] = *(const short8*)(ab + i * 24576 + (kt + 2) * 512);
#pragma unroll
            for (int j = 0; j < 2; j++) bA[j] = *(const short8*)(bb + j * 24576 + (kt + 2) * 512);
        }
        // compute kt+1 from B-buffer
#pragma unroll
        for (int i = 0; i < 4; i++)
#pragma unroll
            for (int j = 0; j < 2; j++)
                acc[i][j] = __builtin_amdgcn_mfma_f32_16x16x32_bf16(aB[i], bB[j], acc[i][j], 0, 0, 0);
    }

#pragma unroll
    for (int i = 0; i < 4; i++)
#pragma unroll
        for (int j = 0; j < 2; j++) {
            const int col = bn + wn + j * 16 + l15;
            const int row0 = bm + wm + i * 16 + quad * 4;
            const int pairi = (col & 127) >> 1;   // same for both lanes of a pair
            const float freq = exp2f(-(float)(2 * pairi) * (13.287712379549449f / 128.0f));
            const bool even = (l15 & 1) == 0;
#pragma unroll
            for (int r = 0; r < 4; r++) {
                const float own = acc[i][j][r];
                const float other = __shfl_xor(own, 1, 64);
                const float pos = (float)((row0 + r) & 2047);
                const float ang = pos * freq;
                const float n = rintf(ang * 0.15915494309189535f);
                const float rr = (ang - n * 6.28125f) - n * 1.9353071795864769e-3f;
                float s, c2;
                __sincosf(rr, &s, &c2);
                const float x1 = even ? own : other;
                const float x2 = even ? other : own;
                const float res = even ? (x1 * c2 - x2 * s) : (x1 * s + x2 * c2);
                if constexpr (MODE == 1) {
                    Cp[(size_t)(row0 + r) * 512 + col] = f2bf(res);
                } else {
                    const int seq = row0 + r;
                    const int b_ = seq >> 11;
                    const int s2 = seq & 2047;
                    Cp[(size_t)(b_ * 4 + (col >> 7)) * 262144 + (s2 >> 5) * 4096
                       + ((s2 >> 4) & 1) * 2048 + ((col >> 5) & 3) * 512
                       + ((col >> 3) & 3) * 128 + (s2 & 15) * 8 + (col & 7)] = f2bf(res);
                }
            }
        }
}

// ---------------------------------------------------------------------------
// fp32-input GEMM, BM=64 BN=128 BK=32 (proven core), MFMA-fragment-major V
// store (vF) for coalesced flash V-operand loads. UNCHANGED from round 6.
// ---------------------------------------------------------------------------
__device__ __forceinline__ void gemm_f32T_vF(
    const float* __restrict__ A, const float* __restrict__ Bw, short* __restrict__ Cp,
    int K, int lda, int ldb, short* As, short* Bs)
{
    const int bm = blockIdx.y * 64;
    const int bn = blockIdx.x * 128;
    const int tid = threadIdx.x;
    const int w = tid >> 6;
    const int lane = tid & 63;
    const int l15 = lane & 15;
    const int quad = lane >> 4;
    const int wm = (w >> 1) * 32;
    const int wn = (w & 1) * 64;
    const int srA = tid >> 2;
    const int scA = (tid & 3) * 8;
    const int srB = tid >> 1;
    const int scB = (tid & 1) * 16;

    f32x4 acc[2][4];
#pragma unroll
    for (int i = 0; i < 2; i++)
#pragma unroll
        for (int j = 0; j < 4; j++) acc[i][j] = zero4();

    for (int k0 = 0; k0 < K; k0 += 32) {
        __syncthreads();
        {
            const float* src = A + (size_t)(bm + srA) * lda + k0 + scA;
            short* dst = &As[srA * 40 + scA];
            const float4* s4 = (const float4*)src;
            float4 f0 = s4[0], f1 = s4[1];
            short8 t0;
            t0[0]=f2bf(f0.x); t0[1]=f2bf(f0.y); t0[2]=f2bf(f0.z); t0[3]=f2bf(f0.w);
            t0[4]=f2bf(f1.x); t0[5]=f2bf(f1.y); t0[6]=f2bf(f1.z); t0[7]=f2bf(f1.w);
            *(short8*)dst = t0;
        }
        {
            const float* src = Bw + (size_t)(bn + srB) * ldb + k0 + scB;
            short* dst = &Bs[srB * 40 + scB];
            const float4* s4 = (const float4*)src;
            float4 f0 = s4[0], f1 = s4[1], f2 = s4[2], f3 = s4[3];
            short8 t0, t1;
            t0[0]=f2bf(f0.x); t0[1]=f2bf(f0.y); t0[2]=f2bf(f0.z); t0[3]=f2bf(f0.w);
            t0[4]=f2bf(f1.x); t0[5]=f2bf(f1.y); t0[6]=f2bf(f1.z); t0[7]=f2bf(f1.w);
            t1[0]=f2bf(f2.x); t1[1]=f2bf(f2.y); t1[2]=f2bf(f2.z); t1[3]=f2bf(f2.w);
            t1[4]=f2bf(f3.x); t1[5]=f2bf(f3.y); t1[6]=f2bf(f3.z); t1[7]=f2bf(f3.w);
            *(short8*)dst = t0; *(short8*)(dst + 8) = t1;
        }
        __syncthreads();

        short8 af[2], bfr[4];
#pragma unroll
        for (int i = 0; i < 2; i++)
            af[i] = *(const short8*)&As[(wm + i * 16 + l15) * 40 + quad * 8];
#pragma unroll
        for (int j = 0; j < 4; j++)
            bfr[j] = *(const short8*)&Bs[(wn + j * 16 + l15) * 40 + quad * 8];
#pragma unroll
        for (int i = 0; i < 2; i++)
#pragma unroll
            for (int j = 0; j < 4; j++)
                acc[i][j] = __builtin_amdgcn_mfma_f32_16x16x32_bf16(af[i], bfr[j], acc[i][j], 0, 0, 0);
    }

#pragma unroll
    for (int i = 0; i < 2; i++)
#pragma unroll
        for (int j = 0; j < 4; j++) {
            const int col = bn + wn + j * 16 + l15;     // d feature 0..511
            const int row0 = bm + wm + i * 16 + quad * 4; // kv seq 0..4095
            const int b_ = row0 >> 11;
            const int s2 = row0 & 2047;
            short4v p;
#pragma unroll
            for (int r = 0; r < 4; r++) p[r] = f2bf(acc[i][j][r]);
            const size_t addr = (size_t)(b_ * 4 + (col >> 7)) * 262144 + (s2 >> 5) * 4096
                              + ((col >> 4) & 7) * 512 + ((s2 >> 3) & 3) * 128
                              + (col & 15) * 8 + (s2 & 7);
            *(short4v*)&Cp[addr] = p;
        }
}

// z=0: qh direct-frag (XCD-affine); z=1: khF likewise; z=2: vF fp32 core.
// Grid (4, 64, 3) = 768 blocks = 3/CU.
__global__ __launch_bounds__(256) void proj_kernel(
    const short* __restrict__ qb, const short* __restrict__ kb, const float* __restrict__ v,
    const short* __restrict__ Wqb, const short* __restrict__ Wkb, const float* __restrict__ Wv,
    short* __restrict__ qh, short* __restrict__ khF, short* __restrict__ vF)
{
    __shared__ short smem[12288];   // used by z2 only
    switch (blockIdx.z) {
    case 0:  gemm_frag_direct<1>(qb, Wqb, qh); break;
    case 1:  gemm_frag_direct<2>(kb, Wkb, khF); break;
    default: gemm_f32T_vF(v + 512, Wv, vF, 512, 1536, 512, smem, smem + 2560); break;
    }
}

// ---------------------------------------------------------------------------
// outproj v2: round-3 M-split applied. out[4096,1536] = attn[4096,512] @
// Wo[:, :512]^T. BM=64 x BN=128, grid (12, 64) = 768 blocks = 3/CU (was
// (12,32) = 384 = 1.5/CU: half the CUs ran 2 sequential blocks -> 2x
// makespan + 1 wave/SIMD latency exposure). Waves 2x2 (32x64), acc[2][4].
// A: bf16 copy staging (64 rows x 32 cols, 16 B/thread); B: fp32->bf16
// convert staging (128 rows x 32 cols) - both from the proven cores.
// ---------------------------------------------------------------------------
__global__ __launch_bounds__(256) void outproj_kernel(
    const short* __restrict__ attn, const float* __restrict__ Wo, float* __restrict__ out)
{
    __shared__ short smem[7680];   // As 64*40=2560 + Bs 128*40=5120
    short* As = smem;
    short* Bs = smem + 2560;
    const int bm = blockIdx.y * 64;
    const int bn = blockIdx.x * 128;
    const int tid = threadIdx.x;
    const int w = tid >> 6;
    const int lane = tid & 63;
    const int l15 = lane & 15;
    const int quad = lane >> 4;
    const int wm = (w >> 1) * 32;
    const int wn = (w & 1) * 64;
    const int srA = tid >> 2;
    const int scA = (tid & 3) * 8;
    const int srB = tid >> 1;
    const int scB = (tid & 1) * 16;
    const int K = 512, lda = 512, ldb = 1536, ldc = 1536;

    f32x4 acc[2][4];
#pragma unroll
    for (int i = 0; i < 2; i++)
#pragma unroll
        for (int j = 0; j < 4; j++) acc[i][j] = zero4();

    for (int k0 = 0; k0 < K; k0 += 32) {
        __syncthreads();
        {
            const short* src = attn + (size_t)(bm + srA) * lda + k0 + scA;
            *(uint4*)&As[srA * 40 + scA] = *(const uint4*)src;
        }
        {
            const float* src = Wo + (size_t)(bn + srB) * ldb + k0 + scB;
            short* dst = &Bs[srB * 40 + scB];
            const float4* s4 = (const float4*)src;
            float4 f0 = s4[0], f1 = s4[1], f2 = s4[2], f3 = s4[3];
            short8 t0, t1;
            t0[0]=f2bf(f0.x); t0[1]=f2bf(f0.y); t0[2]=f2bf(f0.z); t0[3]=f2bf(f0.w);
            t0[4]=f2bf(f1.x); t0[5]=f2bf(f1.y); t0[6]=f2bf(f1.z); t0[7]=f2bf(f1.w);
            t1[0]=f2bf(f2.x); t1[1]=f2bf(f2.y); t1[2]=f2bf(f2.z); t1[3]=f2bf(f2.w);
            t1[4]=f2bf(f3.x); t1[5]=f2bf(f3.y); t1[6]=f2bf(f3.z); t1[7]=f2bf(f3.w);
            *(short8*)dst = t0; *(short8*)(dst + 8) = t1;
        }
        __syncthreads();

        short8 af[2], bfr[4];
#pragma unroll
        for (int i = 0; i < 2; i++)
            af[i] = *(const short8*)&As[(wm + i * 16 + l15) * 40 + quad * 8];
#pragma unroll
        for (int j = 0; j < 4; j++)
            bfr[j] = *(const short8*)&Bs[(wn + j * 16 + l15) * 40 + quad * 8];
#pragma unroll
        for (int i = 0; i < 2; i++)
#pragma unroll
            for (int j = 0; j < 4; j++)
                acc[i][j] = __builtin_amdgcn_mfma_f32_16x16x32_bf16(af[i], bfr[j], acc[i][j], 0, 0, 0);
    }

#pragma unroll
    for (int i = 0; i < 2; i++)
#pragma unroll
        for (int j = 0; j < 4; j++) {
            const int col = bn + wn + j * 16 + l15;
            const int row0 = bm + wm + i * 16 + quad * 4;
#pragma unroll
            for (int r = 0; r < 4; r++)
                out[(size_t)(row0 + r) * ldc + col] = acc[i][j][r];
        }
}

// ---------------------------------------------------------------------------
// Flash attention v12.1: round-6 structure + T5 s_setprio around the two
// MFMA clusters (m191 regime: multi-wave independent blocks, no barrier
// lockstep in the KV loop -> setprio measured +4-7% on attn).
// ---------------------------------------------------------------------------
__global__ __launch_bounds__(256, 4) void flash_kernel(
    const short* __restrict__ qh, const short* __restrict__ khF,
    const short* __restrict__ vF, short* __restrict__ attn)
{
    __shared__ float Os[4][16][128];   // per-wave O partials (32 KB)
    __shared__ short Ps[4][16 * 40];   // per-wave P scratch (5 KB)
    __shared__ float Lp[4][16];        // per-wave row sums

    const int id = blockIdx.x;         // 0..1023
    const int hb = id & 7;
    const int b = hb & 1;
    const int h = hb >> 1;
    const int s = id >> 3;             // 0..127
    const int m = s & 31;
    const int g = s >> 5;              // 0..3
    const int base = (g >> 1) * 32 + m;            // {m, 32+m}
    const int qt = (g & 1) ? (127 - base) : base;  // bijective onto 0..127
    const int tid = threadIdx.x;
    const int w = tid >> 6;
    const int lane = tid & 63;
    const int l15 = lane & 15;
    const int quad = lane >> 4;

    const float scale = 0.08838834764831845f;
    const float MFIX = 24.0f;

    const int q0 = qt * 16;
    const int ntiles = (q0 + 47) >> 5;

    const short* qrow = qh + (size_t)(b * 2048 + q0 + l15) * 512 + h * 128;
    short8 aq[4];
#pragma unroll
    for (int kk = 0; kk < 4; kk++)
        aq[kk] = *(const short8*)&qrow[kk * 32 + quad * 8];

    const short* kfb = khF + (size_t)(b * 4 + h) * 262144 + lane * 8;
    const short* vfb = vF  + (size_t)(b * 4 + h) * 262144 + lane * 8;

    f32x4 o[8];
#pragma unroll
    for (int dt = 0; dt < 8; dt++) o[dt] = zero4();
    float lsum[4] = {0.f, 0.f, 0.f, 0.f};

    short* pw = &Ps[w][0];

    for (int t = w; t < ntiles; t += 4) {
        const int kb0 = t * 32;
        const short* kt_ = kfb + t * 4096;
        const short* vt_ = vfb + t * 4096;

        // ---- S = Q K^T (16q x 32k); K frags = coalesced global loads ----
        f32x4 sc[2];
        __builtin_amdgcn_s_setprio(1);
#pragma unroll
        for (int ct = 0; ct < 2; ct++) {
            sc[ct] = zero4();
#pragma unroll
            for (int kk = 0; kk < 4; kk++) {
                short8 bk = *(const short8*)&kt_[ct * 2048 + kk * 512];
                sc[ct] = __builtin_amdgcn_mfma_f32_16x16x32_bf16(aq[kk], bk, sc[ct], 0, 0, 0);
            }
        }
        __builtin_amdgcn_s_setprio(0);

        // ---- V frags = coalesced global loads ----
        short8 bv[8];
#pragma unroll
        for (int dt = 0; dt < 8; dt++)
            bv[dt] = *(const short8*)&vt_[dt * 512];

        // ---- fixed-max softmax: p = exp(s*scale - M), masked -> 0 ----
        const int rbase = q0 + quad * 4;
        float p[2][4];
#pragma unroll
        for (int ct = 0; ct < 2; ct++) {
            const int kcol = kb0 + ct * 16 + l15;
#pragma unroll
            for (int r = 0; r < 4; r++) {
                const float e = __expf(sc[ct][r] * scale - MFIX);
                const float pv = (kcol > rbase + r) ? 0.0f : e;
                p[ct][r] = pv;
                lsum[r] += pv;
            }
        }

        // ---- P -> per-wave LDS (A-operand layout); intra-wave ----
#pragma unroll
        for (int ct = 0; ct < 2; ct++)
#pragma unroll
            for (int r = 0; r < 4; r++)
                pw[(quad * 4 + r) * 40 + ct * 16 + l15] = f2bf(p[ct][r]);
        short8 ap = *(const short8*)&pw[l15 * 40 + quad * 8];

        // ---- O += P V ----
        __builtin_amdgcn_s_setprio(1);
#pragma unroll
        for (int dt = 0; dt < 8; dt++)
            o[dt] = __builtin_amdgcn_mfma_f32_16x16x32_bf16(ap, bv[dt], o[dt], 0, 0, 0);
        __builtin_amdgcn_s_setprio(0);
    }

    // ---- merge 4 waves: plain sums (common fixed max) ----
#pragma unroll
    for (int r = 0; r < 4; r++) {
        float vsum = lsum[r];
#pragma unroll
        for (int off = 1; off < 16; off <<= 1)
            vsum += __shfl_xor(vsum, off, 64);
        if (l15 == 0) Lp[w][quad * 4 + r] = vsum;
#pragma unroll
        for (int dt = 0; dt < 8; dt++)
            Os[w][quad * 4 + r][dt * 16 + l15] = o[dt][r];
    }
    __syncthreads();

    {
        const int row = tid >> 4;
        const int d0 = (tid & 15) * 8;
        const float L = Lp[0][row] + Lp[1][row] + Lp[2][row] + Lp[3][row];
        const float rL = 1.0f / L;
        short8 ov;
#pragma unroll
        for (int j = 0; j < 8; j++) {
            const float osum = Os[0][row][d0 + j] + Os[1][row][d0 + j]
                             + Os[2][row][d0 + j] + Os[3][row][d0 + j];
            ov[j] = f2bf(osum * rL);
        }
        *(short8*)&attn[(size_t)(b * 2048 + q0 + row) * 512 + h * 128 + d0] = ov;
    }
}

extern "C" void kernel_launch(void* const* d_in, const int* in_sizes, int n_in,
                              void* d_out, int out_size, void* d_ws, size_t ws_size,
                              hipStream_t stream) {
    const float* q  = (const float*)d_in[0];
    const float* k  = (const float*)d_in[1];
    const float* v  = (const float*)d_in[2];
    const float* Wq = (const float*)d_in[3];
    const float* Wk = (const float*)d_in[4];
    const float* Wv = (const float*)d_in[5];
    const float* Wo = (const float*)d_in[6];
    float* out = (float*)d_out;

    const size_t MB = 1024 * 1024;
    // ws (16 MB):
    char* ws = (char*)d_ws;
    short* qh   = (short*)(ws);               // [4096,512] bf16 row-major, 4 MB
    short* khF  = (short*)(ws + 4 * MB);      // fragment-major K, 4 MB
    short* vF   = (short*)(ws + 8 * MB);      // fragment-major V, 4 MB
    short* Wqb  = (short*)(ws + 12 * MB);     // frag-major Wq[0:512,:], dead after proj
    short* Wkb  = (short*)(ws + 13 * MB + 512 * 1024);
    short* attn = (short*)(ws + 12 * MB);     // flash writes over dead Wqb/Wkb
    // d_out (24 MB) as scratch until outproj:
    short* qb   = (short*)d_out;                      // frag-major q, dead after proj
    short* kb   = (short*)((char*)d_out + 12 * MB);   // frag-major k, dead after proj

    // 1) fp32 -> bf16, fragment-major
    convertA_kernel<<<dim3(3072, 1, 4), 256, 0, stream>>>(q, k, Wq, Wk, qb, kb, Wqb, Wkb);
    // 2) projections: z0/z1 direct-fragment GEMM (XCD-affine + prefetch), z2 fp32 core
    proj_kernel<<<dim3(4, 64, 3), 256, 0, stream>>>(qb, kb, v, Wqb, Wkb, Wv, qh, khF, vF);
    // 3) flash attention v12.1 (staging-free + setprio on MFMA clusters)
    flash_kernel<<<dim3(1024, 1, 1), 256, 0, stream>>>(qh, khF, vF, attn);
    // 4) output projection v2 (BM=64, 768 blocks = 3/CU balanced)
    outproj_kernel<<<dim3(12, 64, 1), 256, 0, stream>>>(attn, Wo, out);
}